// Round 5
// baseline (477.532 us; speedup 1.0000x reference)
//
#include <hip/hip_runtime.h>
#include <hip/hip_bf16.h>
#include <math.h>

#define OUT_H 7
#define OUT_W 35
#define NBINS (OUT_H * OUT_W)   // 245
#define NCH   256
#define NROI  512

// NHWC f16 workspace site offsets per level (site = 256 ch = 512 B):
//   l0: 0, l1: 131072, l2: 163840, l3: 172032  (174080 sites = 89.1 MB)

typedef _Float16 h2_t __attribute__((ext_vector_type(2)));
typedef float    f4_t __attribute__((ext_vector_type(4)));  // nontemporal-loadable

static __device__ __forceinline__ h2_t as_h2(unsigned u) {
  return __builtin_bit_cast(h2_t, u);
}
static __device__ __forceinline__ unsigned h2_bits(h2_t v) {
  return __builtin_bit_cast(unsigned, v);
}
static __device__ __forceinline__ unsigned pkrtz_bits(float a, float b) {
  return __builtin_bit_cast(unsigned, __builtin_amdgcn_cvt_pkrtz(a, b));
}
// pack two RTN-rounded halves into one dword (lo = a, hi = b)
static __device__ __forceinline__ unsigned pk_rtn(float a, float b) {
  _Float16 ha = (_Float16)a, hb = (_Float16)b;
  return (unsigned)__builtin_bit_cast(unsigned short, ha) |
         ((unsigned)__builtin_bit_cast(unsigned short, hb) << 16);
}
// sum with lane^32 partner (h2); commutative add -> both halves bit-identical
static __device__ __forceinline__ h2_t sum32(h2_t v) {
  const int p = __shfl_xor((int)h2_bits(v), 32, 64);
  return v + as_h2((unsigned)p);
}

// ---------------------------------------------------------------------------
// Kernel 1: NCHW fp32 -> NHWC f16, tile = 64 ch x 64 hw.  (UNCHANGED this
// round: first-ever counters for it should reflect the known baseline.)
// ---------------------------------------------------------------------------
__global__ __launch_bounds__(256, 8) void transpose_all(
    const float* __restrict__ f0, const float* __restrict__ f1,
    const float* __restrict__ f2, const float* __restrict__ f3,
    ushort* __restrict__ ws)
{
  __shared__ float tile[64 * 65];  // 16.64 KB

  const int t = blockIdx.x;
  int l, rel;
  if      (t < 8192)  { l = 0; rel = t; }
  else if (t < 10240) { l = 1; rel = t - 8192; }
  else if (t < 10752) { l = 2; rel = t - 10240; }
  else                { l = 3; rel = t - 10752; }

  const int HWl  = 65536 >> (2 * l);
  const int lg   = 10 - 2 * l;           // log2(HWl/64)
  const int hwT  = rel & ((1 << lg) - 1);
  const int rest = rel >> lg;
  const int cT   = rest & 3;
  const int b    = rest >> 2;
  const float* fsrc = (l == 0) ? f0 : (l == 1) ? f1 : (l == 2) ? f2 : f3;
  const int pixoff  = (l == 0) ? 0 : (l == 1) ? 131072 : (l == 2) ? 163840 : 172032;
  const int hw0 = hwT << 6;
  const int c0  = cT << 6;

  const int hwq = threadIdx.x & 15;
  const int r0  = threadIdx.x >> 4;  // 0..15
#pragma unroll
  for (int i = 0; i < 4; ++i) {
    const int r = r0 + 16 * i;
    const f4_t v = __builtin_nontemporal_load(
        (const f4_t*)(fsrc + ((size_t)(b * NCH + c0 + r)) * HWl + hw0 + 4 * hwq));
    float* tp = &tile[r * 65 + 4 * hwq];
    tp[0] = v.x; tp[1] = v.y; tp[2] = v.z; tp[3] = v.w;
  }
  __syncthreads();

  const int cq  = threadIdx.x & 15;   // channel quad
  const int hwl = threadIdx.x >> 4;   // 0..15
  ushort* wp = ws + ((size_t)(pixoff + b * HWl + hw0)) * NCH + c0 + cq * 4;
#pragma unroll
  for (int j = 0; j < 4; ++j) {
    const int hw = hwl + 16 * j;
    const float a0 = tile[(4 * cq + 0) * 65 + hw];
    const float a1 = tile[(4 * cq + 1) * 65 + hw];
    const float a2 = tile[(4 * cq + 2) * 65 + hw];
    const float a3 = tile[(4 * cq + 3) * 65 + hw];
    *(uint2*)(wp + (size_t)hw * NCH) =
        make_uint2(pkrtz_bits(a0, a1), pkrtz_bits(a2, a3));
  }
}

// ---------------------------------------------------------------------------
// Kernel 2: rotated RoIAlign gather + mean + max over levels, f16 packed math.
// Pairwise taps: after clamping, x1=x0+1 and y1=y0+1, so the 4 bilinear taps
// are 2 rows x 1024 B of adjacent sites. Lanes 0-31 take the x0 site, lanes
// 32-63 the x1 site, 8 B (4 ch)/lane -> ONE dwordx2 per row covers 2 taps
// (half the VMEM instrs of round 4, same bytes). Per-lane weight select via
// v_perm; per-level cross-half combine via shfl_xor(32).
// Split into 2 dispatches (n_base 0/256) so transpose_all can surface in the
// profiler's top-5 with counters.
// ---------------------------------------------------------------------------
__global__ __launch_bounds__(256, 8) void roi_align_rotated_max(
    const ushort* __restrict__ ft,   // NHWC f16 (bits), all levels
    const float* __restrict__ rois,  // [512][6]
    float* __restrict__ out,         // [512][256][7][35]
    int n_base)
{
  __shared__ uint4    s_desc[OUT_W * 16];  // 8960 B: {byte_off, wy0, wy1, pad}
  __shared__ unsigned s_out[OUT_W * 70];   // 9800 B: f16 pairs, pitch 70 uints

  const int g    = blockIdx.x;
  const int slot = g & 7;
  const int rest = g >> 3;
  const int hc   = rest % 14;
  const int oh   = hc % 7;
  const int ch2  = hc / 7;                 // channel half (0: ch 0-127, 1: 128-255)
  const int n    = n_base + slot + 8 * (rest / 14);

  const float* R = rois + n * 6;
  const int b = (int)R[0];
  const float ct = (float)cos((double)R[5]);
  const float st = (float)sin((double)R[5]);

  // ---- Phase 1: 560 sample descriptors (independent of ch2) ----
  for (int j = threadIdx.x; j < OUT_W * 16; j += 256) {
    const int ow = j >> 4;
    const int ls = j & 15;
    const int l  = ls >> 2;
    const int s  = ls & 3;
    const int sy = s >> 1, sx = s & 1;

    const int   Hl     = 256 >> l;
    const float scale  = 0.25f / (float)(1 << l);
    const int   pixoff = (l == 0) ? 0 : (l == 1) ? 131072 : (l == 2) ? 163840 : 172032;

    // mirror reference f32 op order exactly; no FMA contraction
    const float cx = __fmul_rn(R[1], scale);
    const float cy = __fmul_rn(R[2], scale);
    const float w  = fmaxf(__fmul_rn(R[3], scale), 1.0f);
    const float h  = fmaxf(__fmul_rn(R[4], scale), 1.0f);
    const float bin_h = __fdiv_rn(h, (float)OUT_H);
    const float bin_w = __fdiv_rn(w, (float)OUT_W);
    const float gy = (float)oh + (sy ? 0.75f : 0.25f);
    const float gx = (float)ow + (sx ? 0.75f : 0.25f);
    const float yy = __fadd_rn(__fmul_rn(-h, 0.5f), __fmul_rn(gy, bin_h));
    const float xx = __fadd_rn(__fmul_rn(-w, 0.5f), __fmul_rn(gx, bin_w));
    const float x = __fadd_rn(__fsub_rn(__fmul_rn(xx, ct), __fmul_rn(yy, st)), cx);
    const float y = __fadd_rn(__fadd_rn(__fmul_rn(xx, st), __fmul_rn(yy, ct)), cy);

    const bool valid = (y >= -1.0f) && (y <= (float)Hl) &&
                       (x >= -1.0f) && (x <= (float)Hl);
    float yc = fminf(fmaxf(y, 0.0f), (float)(Hl - 1));
    float xc = fminf(fmaxf(x, 0.0f), (float)(Hl - 1));
    int y0 = (int)floorf(yc);
    int x0 = (int)floorf(xc);
    float ly = yc - (float)y0;
    float lx = xc - (float)x0;
    if (y0 >= Hl - 1) { y0 = Hl - 2; ly = 1.0f; }
    if (x0 >= Hl - 1) { x0 = Hl - 2; lx = 1.0f; }
    const float hy = 1.0f - ly, hx = 1.0f - lx;
    const float sc = valid ? 0.25f : 0.0f;  // fold 1/ns^2 sample mean

    s_desc[j] = make_uint4(
        (unsigned)((pixoff + (b * Hl + y0) * Hl + x0) * (NCH * 2)),  // byte off
        pk_rtn(sc * hy * hx, sc * hy * lx),   // y0 row: (x0 w, x1 w)
        pk_rtn(sc * ly * hx, sc * ly * lx),   // y1 row: (x0 w, x1 w)
        0u);
  }
  __syncthreads();

  const int wv   = threadIdx.x >> 6;
  const int lane = threadIdx.x & 63;
  // lanes 0-31: x0 site; lanes 32-63: x1 site (adjacent, +512 B). 4 ch/lane.
  const char* ftb = (const char*)ft + ch2 * 256 + lane * 8 +
                    ((lane >= 32) ? 256 : 0);
  // v_perm selector: low half of weight word for x0 lanes, high half for x1
  const unsigned wsel = (lane < 32) ? 0x01000100u : 0x03020302u;

  for (int ow = wv; ow < OUT_W; ow += 4) {
    h2_t m0, m1;
#pragma unroll
    for (int l = 0; l < 4; ++l) {
      const int rowb = 131072 >> l;  // (256>>l)*512 bytes

      // batch: 4 descriptor reads
      const uint4 q0 = s_desc[ow * 16 + l * 4 + 0];
      const uint4 q1 = s_desc[ow * 16 + l * 4 + 1];
      const uint4 q2 = s_desc[ow * 16 + l * 4 + 2];
      const uint4 q3 = s_desc[ow * 16 + l * 4 + 3];

      // batch: issue all 8 row loads (8 dwordx2 in flight, covers 16 taps)
      uint2 d[8];
      {
        const char* p0 = ftb + (int)q0.x;
        const char* p1 = ftb + (int)q1.x;
        const char* p2 = ftb + (int)q2.x;
        const char* p3 = ftb + (int)q3.x;
        d[0] = *(const uint2*)(p0);         // s0 y0 row
        d[1] = *(const uint2*)(p0 + rowb);  // s0 y1 row
        d[2] = *(const uint2*)(p1);
        d[3] = *(const uint2*)(p1 + rowb);
        d[4] = *(const uint2*)(p2);
        d[5] = *(const uint2*)(p2 + rowb);
        d[6] = *(const uint2*)(p3);
        d[7] = *(const uint2*)(p3 + rowb);
      }

      // 16 pk_fma; per lane-half: its x-column's taps in reference row order
      h2_t a0 = {(_Float16)0, (_Float16)0};
      h2_t a1 = {(_Float16)0, (_Float16)0};
      {
        const h2_t wy0 = as_h2(__builtin_amdgcn_perm(q0.y, q0.y, wsel));
        const h2_t wy1 = as_h2(__builtin_amdgcn_perm(q0.z, q0.z, wsel));
        a0 = wy0 * as_h2(d[0].x) + a0;  a1 = wy0 * as_h2(d[0].y) + a1;
        a0 = wy1 * as_h2(d[1].x) + a0;  a1 = wy1 * as_h2(d[1].y) + a1;
      }
      {
        const h2_t wy0 = as_h2(__builtin_amdgcn_perm(q1.y, q1.y, wsel));
        const h2_t wy1 = as_h2(__builtin_amdgcn_perm(q1.z, q1.z, wsel));
        a0 = wy0 * as_h2(d[2].x) + a0;  a1 = wy0 * as_h2(d[2].y) + a1;
        a0 = wy1 * as_h2(d[3].x) + a0;  a1 = wy1 * as_h2(d[3].y) + a1;
      }
      {
        const h2_t wy0 = as_h2(__builtin_amdgcn_perm(q2.y, q2.y, wsel));
        const h2_t wy1 = as_h2(__builtin_amdgcn_perm(q2.z, q2.z, wsel));
        a0 = wy0 * as_h2(d[4].x) + a0;  a1 = wy0 * as_h2(d[4].y) + a1;
        a0 = wy1 * as_h2(d[5].x) + a0;  a1 = wy1 * as_h2(d[5].y) + a1;
      }
      {
        const h2_t wy0 = as_h2(__builtin_amdgcn_perm(q3.y, q3.y, wsel));
        const h2_t wy1 = as_h2(__builtin_amdgcn_perm(q3.z, q3.z, wsel));
        a0 = wy0 * as_h2(d[6].x) + a0;  a1 = wy0 * as_h2(d[6].y) + a1;
        a0 = wy1 * as_h2(d[7].x) + a0;  a1 = wy1 * as_h2(d[7].y) + a1;
      }

      // combine x0 + x1 halves (bit-identical in both halves), then level max
      const h2_t r0 = sum32(a0), r1 = sum32(a1);
      if (l == 0) { m0 = r0; m1 = r1; }
      else {
        m0 = __builtin_elementwise_max(m0, r0);
        m1 = __builtin_elementwise_max(m1, r1);
      }
    }
    if (lane < 32)  // halves hold duplicates; one writer per ch quad
      *(uint2*)&s_out[ow * 70 + lane * 2] = make_uint2(h2_bits(m0), h2_bits(m1));
  }
  __syncthreads();

  // ---- near-coalesced transposed write-out (f16 -> f32) ----
  const size_t outbase = (size_t)n * NCH * NBINS + (size_t)ch2 * 128 * NBINS +
                         (size_t)oh * OUT_W;
  const _Float16* sh = (const _Float16*)s_out;
#pragma unroll
  for (int j = 0; j < 18; ++j) {
    const int idx = threadIdx.x + j * 256;  // 0..4607, guard 4480
    if (idx < 128 * OUT_W) {
      const int cc = idx / OUT_W;           // magic-mul const div
      const int ww = idx - cc * OUT_W;
      out[outbase + (size_t)cc * NBINS + ww] = (float)sh[ww * 140 + cc];
    }
  }
}

// ---------------------------------------------------------------------------
extern "C" void kernel_launch(void* const* d_in, const int* in_sizes, int n_in,
                              void* d_out, int out_size, void* d_ws, size_t ws_size,
                              hipStream_t stream) {
  const float* f0 = (const float*)d_in[0];
  const float* f1 = (const float*)d_in[1];
  const float* f2 = (const float*)d_in[2];
  const float* f3 = (const float*)d_in[3];
  const float* rois = (const float*)d_in[4];
  ushort* ws = (ushort*)d_ws;
  float* out = (float*)d_out;

  transpose_all<<<10880, 256, 0, stream>>>(f0, f1, f2, f3, ws);
  roi_align_rotated_max<<<3584, 256, 0, stream>>>(ws, rois, out, 0);
  roi_align_rotated_max<<<3584, 256, 0, stream>>>(ws, rois, out, 256);
}

// Round 6
// 385.909 us; speedup vs baseline: 1.2374x; 1.2374x over previous
//
#include <hip/hip_runtime.h>
#include <hip/hip_bf16.h>
#include <math.h>

#define OUT_H 7
#define OUT_W 35
#define NBINS (OUT_H * OUT_W)   // 245
#define NCH   256
#define NROI  512

// NHWC f16 workspace site offsets per level (site = 256 ch = 512 B):
//   l0: 0, l1: 131072, l2: 163840, l3: 172032  (174080 sites = 89.1 MB)

typedef _Float16 h2_t __attribute__((ext_vector_type(2)));
typedef float    f4_t __attribute__((ext_vector_type(4)));  // nontemporal-loadable

static __device__ __forceinline__ h2_t as_h2(unsigned u) {
  return __builtin_bit_cast(h2_t, u);
}
static __device__ __forceinline__ unsigned h2_bits(h2_t v) {
  return __builtin_bit_cast(unsigned, v);
}
static __device__ __forceinline__ unsigned pkrtz_bits(float a, float b) {
  return __builtin_bit_cast(unsigned, __builtin_amdgcn_cvt_pkrtz(a, b));
}
// pack two RTN-rounded halves into one dword (lo = a, hi = b)
static __device__ __forceinline__ unsigned pk_rtn(float a, float b) {
  _Float16 ha = (_Float16)a, hb = (_Float16)b;
  return (unsigned)__builtin_bit_cast(unsigned short, ha) |
         ((unsigned)__builtin_bit_cast(unsigned short, hb) << 16);
}

// ---------------------------------------------------------------------------
// Kernel 1: NCHW fp32 -> NHWC f16, tile = 64 ch x 64 hw.  UNCHANGED (so its
// first-ever counters, if it surfaces this round, reflect the known config).
// ---------------------------------------------------------------------------
__global__ __launch_bounds__(256, 8) void transpose_all(
    const float* __restrict__ f0, const float* __restrict__ f1,
    const float* __restrict__ f2, const float* __restrict__ f3,
    ushort* __restrict__ ws)
{
  __shared__ float tile[64 * 65];  // 16.64 KB

  const int t = blockIdx.x;
  int l, rel;
  if      (t < 8192)  { l = 0; rel = t; }
  else if (t < 10240) { l = 1; rel = t - 8192; }
  else if (t < 10752) { l = 2; rel = t - 10240; }
  else                { l = 3; rel = t - 10752; }

  const int HWl  = 65536 >> (2 * l);
  const int lg   = 10 - 2 * l;           // log2(HWl/64)
  const int hwT  = rel & ((1 << lg) - 1);
  const int rest = rel >> lg;
  const int cT   = rest & 3;
  const int b    = rest >> 2;
  const float* fsrc = (l == 0) ? f0 : (l == 1) ? f1 : (l == 2) ? f2 : f3;
  const int pixoff  = (l == 0) ? 0 : (l == 1) ? 131072 : (l == 2) ? 163840 : 172032;
  const int hw0 = hwT << 6;
  const int c0  = cT << 6;

  const int hwq = threadIdx.x & 15;
  const int r0  = threadIdx.x >> 4;  // 0..15
#pragma unroll
  for (int i = 0; i < 4; ++i) {
    const int r = r0 + 16 * i;
    const f4_t v = __builtin_nontemporal_load(
        (const f4_t*)(fsrc + ((size_t)(b * NCH + c0 + r)) * HWl + hw0 + 4 * hwq));
    float* tp = &tile[r * 65 + 4 * hwq];
    tp[0] = v.x; tp[1] = v.y; tp[2] = v.z; tp[3] = v.w;
  }
  __syncthreads();

  const int cq  = threadIdx.x & 15;   // channel quad
  const int hwl = threadIdx.x >> 4;   // 0..15
  ushort* wp = ws + ((size_t)(pixoff + b * HWl + hw0)) * NCH + c0 + cq * 4;
#pragma unroll
  for (int j = 0; j < 4; ++j) {
    const int hw = hwl + 16 * j;
    const float a0 = tile[(4 * cq + 0) * 65 + hw];
    const float a1 = tile[(4 * cq + 1) * 65 + hw];
    const float a2 = tile[(4 * cq + 2) * 65 + hw];
    const float a3 = tile[(4 * cq + 3) * 65 + hw];
    *(uint2*)(wp + (size_t)hw * NCH) =
        make_uint2(pkrtz_bits(a0, a1), pkrtz_bits(a2, a3));
  }
}

// ---------------------------------------------------------------------------
// Kernel 2: EXACT round-4 body (proven 156 us full-size): per l-level, batch
// 4 descriptor reads + 16 dword tap loads into regs, then 16 pk_fma in the
// reference order. ONLY change: n_base param + 2-way dispatch split, to
// (a) isolate round-5's confound and (b) let transpose_all surface in top-5.
// ---------------------------------------------------------------------------
__global__ __launch_bounds__(256, 8) void roi_align_rotated_max(
    const ushort* __restrict__ ft,   // NHWC f16 (bits), all levels
    const float* __restrict__ rois,  // [512][6]
    float* __restrict__ out,         // [512][256][7][35]
    int n_base)
{
  __shared__ uint4    s_desc[OUT_W * 16];  // 8960 B: {byte_off, w01, w23, pad}
  __shared__ unsigned s_out[OUT_W * 66];   // 9240 B: f16 pairs, pitch 66 uints

  const int g    = blockIdx.x;
  const int slot = g & 7;
  const int rest = g >> 3;
  const int hc   = rest % 14;
  const int oh   = hc % 7;
  const int ch2  = hc / 7;                 // channel half (0: ch 0-127, 1: 128-255)
  const int n    = n_base + slot + 8 * (rest / 14);

  const float* R = rois + n * 6;
  const int b = (int)R[0];
  const float ct = (float)cos((double)R[5]);
  const float st = (float)sin((double)R[5]);

  // ---- Phase 1: 560 sample descriptors (independent of ch2) ----
  for (int j = threadIdx.x; j < OUT_W * 16; j += 256) {
    const int ow = j >> 4;
    const int ls = j & 15;
    const int l  = ls >> 2;
    const int s  = ls & 3;
    const int sy = s >> 1, sx = s & 1;

    const int   Hl     = 256 >> l;
    const float scale  = 0.25f / (float)(1 << l);
    const int   pixoff = (l == 0) ? 0 : (l == 1) ? 131072 : (l == 2) ? 163840 : 172032;

    // mirror reference f32 op order exactly; no FMA contraction
    const float cx = __fmul_rn(R[1], scale);
    const float cy = __fmul_rn(R[2], scale);
    const float w  = fmaxf(__fmul_rn(R[3], scale), 1.0f);
    const float h  = fmaxf(__fmul_rn(R[4], scale), 1.0f);
    const float bin_h = __fdiv_rn(h, (float)OUT_H);
    const float bin_w = __fdiv_rn(w, (float)OUT_W);
    const float gy = (float)oh + (sy ? 0.75f : 0.25f);
    const float gx = (float)ow + (sx ? 0.75f : 0.25f);
    const float yy = __fadd_rn(__fmul_rn(-h, 0.5f), __fmul_rn(gy, bin_h));
    const float xx = __fadd_rn(__fmul_rn(-w, 0.5f), __fmul_rn(gx, bin_w));
    const float x = __fadd_rn(__fsub_rn(__fmul_rn(xx, ct), __fmul_rn(yy, st)), cx);
    const float y = __fadd_rn(__fadd_rn(__fmul_rn(xx, st), __fmul_rn(yy, ct)), cy);

    const bool valid = (y >= -1.0f) && (y <= (float)Hl) &&
                       (x >= -1.0f) && (x <= (float)Hl);
    float yc = fminf(fmaxf(y, 0.0f), (float)(Hl - 1));
    float xc = fminf(fmaxf(x, 0.0f), (float)(Hl - 1));
    int y0 = (int)floorf(yc);
    int x0 = (int)floorf(xc);
    float ly = yc - (float)y0;
    float lx = xc - (float)x0;
    if (y0 >= Hl - 1) { y0 = Hl - 2; ly = 1.0f; }
    if (x0 >= Hl - 1) { x0 = Hl - 2; lx = 1.0f; }
    const float hy = 1.0f - ly, hx = 1.0f - lx;
    const float sc = valid ? 0.25f : 0.0f;  // fold 1/ns^2 sample mean

    s_desc[j] = make_uint4(
        (unsigned)((pixoff + (b * Hl + y0) * Hl + x0) * (NCH * 2)),  // byte off
        pk_rtn(sc * hy * hx, sc * hy * lx),
        pk_rtn(sc * ly * hx, sc * ly * lx), 0u);
  }
  __syncthreads();

  const int  wv   = threadIdx.x >> 6;
  const int  lane = threadIdx.x & 63;
  const char* ftb = (const char*)ft + ch2 * 256 + lane * 4;  // 2 channels / lane

  for (int ow = wv; ow < OUT_W; ow += 4) {
    h2_t m;
#pragma unroll
    for (int l = 0; l < 4; ++l) {
      const int rowb = 131072 >> l;  // (256>>l)*512 bytes

      // batch: 4 descriptor reads
      uint4 q0 = s_desc[ow * 16 + l * 4 + 0];
      uint4 q1 = s_desc[ow * 16 + l * 4 + 1];
      uint4 q2 = s_desc[ow * 16 + l * 4 + 2];
      uint4 q3 = s_desc[ow * 16 + l * 4 + 3];

      // batch: issue all 16 tap loads (16 VMEM in flight)
      unsigned tv[16];
      {
        const char* p0 = ftb + (int)q0.x;
        const char* p1 = ftb + (int)q1.x;
        const char* p2 = ftb + (int)q2.x;
        const char* p3 = ftb + (int)q3.x;
        tv[ 0] = *(const unsigned*)(p0);
        tv[ 1] = *(const unsigned*)(p0 + 512);
        tv[ 2] = *(const unsigned*)(p0 + rowb);
        tv[ 3] = *(const unsigned*)(p0 + rowb + 512);
        tv[ 4] = *(const unsigned*)(p1);
        tv[ 5] = *(const unsigned*)(p1 + 512);
        tv[ 6] = *(const unsigned*)(p1 + rowb);
        tv[ 7] = *(const unsigned*)(p1 + rowb + 512);
        tv[ 8] = *(const unsigned*)(p2);
        tv[ 9] = *(const unsigned*)(p2 + 512);
        tv[10] = *(const unsigned*)(p2 + rowb);
        tv[11] = *(const unsigned*)(p2 + rowb + 512);
        tv[12] = *(const unsigned*)(p3);
        tv[13] = *(const unsigned*)(p3 + 512);
        tv[14] = *(const unsigned*)(p3 + rowb);
        tv[15] = *(const unsigned*)(p3 + rowb + 512);
      }

      // 16 pk_fma in the exact reference accumulation order
      h2_t a = {(_Float16)0, (_Float16)0};
      {
        const h2_t w01 = as_h2(q0.y), w23 = as_h2(q0.z);
        a = __builtin_shufflevector(w01, w01, 0, 0) * as_h2(tv[ 0]) + a;
        a = __builtin_shufflevector(w01, w01, 1, 1) * as_h2(tv[ 1]) + a;
        a = __builtin_shufflevector(w23, w23, 0, 0) * as_h2(tv[ 2]) + a;
        a = __builtin_shufflevector(w23, w23, 1, 1) * as_h2(tv[ 3]) + a;
      }
      {
        const h2_t w01 = as_h2(q1.y), w23 = as_h2(q1.z);
        a = __builtin_shufflevector(w01, w01, 0, 0) * as_h2(tv[ 4]) + a;
        a = __builtin_shufflevector(w01, w01, 1, 1) * as_h2(tv[ 5]) + a;
        a = __builtin_shufflevector(w23, w23, 0, 0) * as_h2(tv[ 6]) + a;
        a = __builtin_shufflevector(w23, w23, 1, 1) * as_h2(tv[ 7]) + a;
      }
      {
        const h2_t w01 = as_h2(q2.y), w23 = as_h2(q2.z);
        a = __builtin_shufflevector(w01, w01, 0, 0) * as_h2(tv[ 8]) + a;
        a = __builtin_shufflevector(w01, w01, 1, 1) * as_h2(tv[ 9]) + a;
        a = __builtin_shufflevector(w23, w23, 0, 0) * as_h2(tv[10]) + a;
        a = __builtin_shufflevector(w23, w23, 1, 1) * as_h2(tv[11]) + a;
      }
      {
        const h2_t w01 = as_h2(q3.y), w23 = as_h2(q3.z);
        a = __builtin_shufflevector(w01, w01, 0, 0) * as_h2(tv[12]) + a;
        a = __builtin_shufflevector(w01, w01, 1, 1) * as_h2(tv[13]) + a;
        a = __builtin_shufflevector(w23, w23, 0, 0) * as_h2(tv[14]) + a;
        a = __builtin_shufflevector(w23, w23, 1, 1) * as_h2(tv[15]) + a;
      }

      if (l == 0) m = a;
      else        m = __builtin_elementwise_max(m, a);
    }
    s_out[ow * 66 + lane] = h2_bits(m);  // 2-way banks, free
  }
  __syncthreads();

  // ---- near-coalesced transposed write-out (f16 -> f32) ----
  const size_t outbase = (size_t)n * NCH * NBINS + (size_t)ch2 * 128 * NBINS +
                         (size_t)oh * OUT_W;
  const _Float16* sh = (const _Float16*)s_out;
#pragma unroll
  for (int j = 0; j < 18; ++j) {
    const int idx = threadIdx.x + j * 256;  // 0..4607, guard 4480
    if (idx < 128 * OUT_W) {
      const int cc = idx / OUT_W;           // magic-mul const div
      const int ww = idx - cc * OUT_W;
      out[outbase + (size_t)cc * NBINS + ww] = (float)sh[ww * 132 + cc];
    }
  }
}

// ---------------------------------------------------------------------------
extern "C" void kernel_launch(void* const* d_in, const int* in_sizes, int n_in,
                              void* d_out, int out_size, void* d_ws, size_t ws_size,
                              hipStream_t stream) {
  const float* f0 = (const float*)d_in[0];
  const float* f1 = (const float*)d_in[1];
  const float* f2 = (const float*)d_in[2];
  const float* f3 = (const float*)d_in[3];
  const float* rois = (const float*)d_in[4];
  ushort* ws = (ushort*)d_ws;
  float* out = (float*)d_out;

  transpose_all<<<10880, 256, 0, stream>>>(f0, f1, f2, f3, ws);
  roi_align_rotated_max<<<3584, 256, 0, stream>>>(ws, rois, out, 0);
  roi_align_rotated_max<<<3584, 256, 0, stream>>>(ws, rois, out, 256);
}

// Round 7
// 378.252 us; speedup vs baseline: 1.2625x; 1.0202x over previous
//
#include <hip/hip_runtime.h>
#include <hip/hip_bf16.h>
#include <math.h>

#define OUT_H 7
#define OUT_W 35
#define NBINS (OUT_H * OUT_W)   // 245
#define NCH   256
#define NROI  512

// NHWC f16 workspace site offsets per level (site = 256 ch = 512 B):
//   l0: 0, l1: 131072, l2: 163840, l3: 172032  (174080 sites = 89.1 MB)

typedef _Float16 h2_t __attribute__((ext_vector_type(2)));
typedef float    f4_t __attribute__((ext_vector_type(4)));  // nontemporal-loadable

static __device__ __forceinline__ h2_t as_h2(unsigned u) {
  return __builtin_bit_cast(h2_t, u);
}
static __device__ __forceinline__ unsigned h2_bits(h2_t v) {
  return __builtin_bit_cast(unsigned, v);
}
static __device__ __forceinline__ unsigned pkrtz_bits(float a, float b) {
  return __builtin_bit_cast(unsigned, __builtin_amdgcn_cvt_pkrtz(a, b));
}
// pack two RTN-rounded halves into one dword (lo = a, hi = b)
static __device__ __forceinline__ unsigned pk_rtn(float a, float b) {
  _Float16 ha = (_Float16)a, hb = (_Float16)b;
  return (unsigned)__builtin_bit_cast(unsigned short, ha) |
         ((unsigned)__builtin_bit_cast(unsigned short, hb) << 16);
}

// ---------------------------------------------------------------------------
// Kernel 1: NCHW fp32 -> NHWC f16, tile = 64 ch x 64 hw.  UNCHANGED.
// Bounded < 88 us by round-6 top-5 displacement; BW floor ~42 us.
// ---------------------------------------------------------------------------
__global__ __launch_bounds__(256, 8) void transpose_all(
    const float* __restrict__ f0, const float* __restrict__ f1,
    const float* __restrict__ f2, const float* __restrict__ f3,
    ushort* __restrict__ ws)
{
  __shared__ float tile[64 * 65];  // 16.64 KB

  const int t = blockIdx.x;
  int l, rel;
  if      (t < 8192)  { l = 0; rel = t; }
  else if (t < 10240) { l = 1; rel = t - 8192; }
  else if (t < 10752) { l = 2; rel = t - 10240; }
  else                { l = 3; rel = t - 10752; }

  const int HWl  = 65536 >> (2 * l);
  const int lg   = 10 - 2 * l;           // log2(HWl/64)
  const int hwT  = rel & ((1 << lg) - 1);
  const int rest = rel >> lg;
  const int cT   = rest & 3;
  const int b    = rest >> 2;
  const float* fsrc = (l == 0) ? f0 : (l == 1) ? f1 : (l == 2) ? f2 : f3;
  const int pixoff  = (l == 0) ? 0 : (l == 1) ? 131072 : (l == 2) ? 163840 : 172032;
  const int hw0 = hwT << 6;
  const int c0  = cT << 6;

  const int hwq = threadIdx.x & 15;
  const int r0  = threadIdx.x >> 4;  // 0..15
#pragma unroll
  for (int i = 0; i < 4; ++i) {
    const int r = r0 + 16 * i;
    const f4_t v = __builtin_nontemporal_load(
        (const f4_t*)(fsrc + ((size_t)(b * NCH + c0 + r)) * HWl + hw0 + 4 * hwq));
    float* tp = &tile[r * 65 + 4 * hwq];
    tp[0] = v.x; tp[1] = v.y; tp[2] = v.z; tp[3] = v.w;
  }
  __syncthreads();

  const int cq  = threadIdx.x & 15;   // channel quad
  const int hwl = threadIdx.x >> 4;   // 0..15
  ushort* wp = ws + ((size_t)(pixoff + b * HWl + hw0)) * NCH + c0 + cq * 4;
#pragma unroll
  for (int j = 0; j < 4; ++j) {
    const int hw = hwl + 16 * j;
    const float a0 = tile[(4 * cq + 0) * 65 + hw];
    const float a1 = tile[(4 * cq + 1) * 65 + hw];
    const float a2 = tile[(4 * cq + 2) * 65 + hw];
    const float a3 = tile[(4 * cq + 3) * 65 + hw];
    *(uint2*)(wp + (size_t)hw * NCH) =
        make_uint2(pkrtz_bits(a0, a1), pkrtz_bits(a2, a3));
  }
}

// helper: issue 16 tap loads for one level (4 samples x 4 corners)
#define ISSUE16(TV, Q0, Q1, Q2, Q3, ROWB)                      \
  {                                                            \
    const char* p0 = ftb + (int)Q0.x;                          \
    const char* p1 = ftb + (int)Q1.x;                          \
    const char* p2 = ftb + (int)Q2.x;                          \
    const char* p3 = ftb + (int)Q3.x;                          \
    TV[ 0] = *(const unsigned*)(p0);                           \
    TV[ 1] = *(const unsigned*)(p0 + 512);                     \
    TV[ 2] = *(const unsigned*)(p0 + (ROWB));                  \
    TV[ 3] = *(const unsigned*)(p0 + (ROWB) + 512);            \
    TV[ 4] = *(const unsigned*)(p1);                           \
    TV[ 5] = *(const unsigned*)(p1 + 512);                     \
    TV[ 6] = *(const unsigned*)(p1 + (ROWB));                  \
    TV[ 7] = *(const unsigned*)(p1 + (ROWB) + 512);            \
    TV[ 8] = *(const unsigned*)(p2);                           \
    TV[ 9] = *(const unsigned*)(p2 + 512);                     \
    TV[10] = *(const unsigned*)(p2 + (ROWB));                  \
    TV[11] = *(const unsigned*)(p2 + (ROWB) + 512);            \
    TV[12] = *(const unsigned*)(p3);                           \
    TV[13] = *(const unsigned*)(p3 + 512);                     \
    TV[14] = *(const unsigned*)(p3 + (ROWB));                  \
    TV[15] = *(const unsigned*)(p3 + (ROWB) + 512);            \
  }

// helper: 16 pk_fma in the exact reference accumulation order
#define FMA16(A, TV, Q0, Q1, Q2, Q3)                                        \
  {                                                                         \
    {                                                                       \
      const h2_t w01 = as_h2(Q0.y), w23 = as_h2(Q0.z);                      \
      A = __builtin_shufflevector(w01, w01, 0, 0) * as_h2(TV[ 0]) + A;      \
      A = __builtin_shufflevector(w01, w01, 1, 1) * as_h2(TV[ 1]) + A;      \
      A = __builtin_shufflevector(w23, w23, 0, 0) * as_h2(TV[ 2]) + A;      \
      A = __builtin_shufflevector(w23, w23, 1, 1) * as_h2(TV[ 3]) + A;      \
    }                                                                       \
    {                                                                       \
      const h2_t w01 = as_h2(Q1.y), w23 = as_h2(Q1.z);                      \
      A = __builtin_shufflevector(w01, w01, 0, 0) * as_h2(TV[ 4]) + A;      \
      A = __builtin_shufflevector(w01, w01, 1, 1) * as_h2(TV[ 5]) + A;      \
      A = __builtin_shufflevector(w23, w23, 0, 0) * as_h2(TV[ 6]) + A;      \
      A = __builtin_shufflevector(w23, w23, 1, 1) * as_h2(TV[ 7]) + A;      \
    }                                                                       \
    {                                                                       \
      const h2_t w01 = as_h2(Q2.y), w23 = as_h2(Q2.z);                      \
      A = __builtin_shufflevector(w01, w01, 0, 0) * as_h2(TV[ 8]) + A;      \
      A = __builtin_shufflevector(w01, w01, 1, 1) * as_h2(TV[ 9]) + A;      \
      A = __builtin_shufflevector(w23, w23, 0, 0) * as_h2(TV[10]) + A;      \
      A = __builtin_shufflevector(w23, w23, 1, 1) * as_h2(TV[11]) + A;      \
    }                                                                       \
    {                                                                       \
      const h2_t w01 = as_h2(Q3.y), w23 = as_h2(Q3.z);                      \
      A = __builtin_shufflevector(w01, w01, 0, 0) * as_h2(TV[12]) + A;      \
      A = __builtin_shufflevector(w01, w01, 1, 1) * as_h2(TV[13]) + A;      \
      A = __builtin_shufflevector(w23, w23, 0, 0) * as_h2(TV[14]) + A;      \
      A = __builtin_shufflevector(w23, w23, 1, 1) * as_h2(TV[15]) + A;      \
    }                                                                       \
  }

// ---------------------------------------------------------------------------
// Kernel 2: rotated RoIAlign gather + mean + max over levels, f16 packed math.
// Round-4 arithmetic (bit-identical), software-pipelined across levels:
// level l+1's 16 tap loads are issued BEFORE level l's FMAs run, keeping
// 16-32 VMEM in flight continuously (removes per-level vmcnt-drain bubble).
// __launch_bounds__(256,7): ~70-reg budget avoids forced spills; 7 blocks/CU
// = 87.5% occupancy cap vs ~79% measured at 8 -> negligible loss.
// Single 7168-block dispatch (2-way split measured +20 us tail, reverted).
// ---------------------------------------------------------------------------
__global__ __launch_bounds__(256, 7) void roi_align_rotated_max(
    const ushort* __restrict__ ft,   // NHWC f16 (bits), all levels
    const float* __restrict__ rois,  // [512][6]
    float* __restrict__ out)         // [512][256][7][35]
{
  __shared__ uint4    s_desc[OUT_W * 16];  // 8960 B: {byte_off, w01, w23, pad}
  __shared__ unsigned s_out[OUT_W * 66];   // 9240 B: f16 pairs, pitch 66 uints

  const int g    = blockIdx.x;
  const int slot = g & 7;
  const int rest = g >> 3;
  const int hc   = rest % 14;
  const int oh   = hc % 7;
  const int ch2  = hc / 7;                 // channel half (0: ch 0-127, 1: 128-255)
  const int n    = slot + 8 * (rest / 14);

  const float* R = rois + n * 6;
  const int b = (int)R[0];
  const float ct = (float)cos((double)R[5]);
  const float st = (float)sin((double)R[5]);

  // ---- Phase 1: 560 sample descriptors (independent of ch2) ----
  for (int j = threadIdx.x; j < OUT_W * 16; j += 256) {
    const int ow = j >> 4;
    const int ls = j & 15;
    const int l  = ls >> 2;
    const int s  = ls & 3;
    const int sy = s >> 1, sx = s & 1;

    const int   Hl     = 256 >> l;
    const float scale  = 0.25f / (float)(1 << l);
    const int   pixoff = (l == 0) ? 0 : (l == 1) ? 131072 : (l == 2) ? 163840 : 172032;

    // mirror reference f32 op order exactly; no FMA contraction
    const float cx = __fmul_rn(R[1], scale);
    const float cy = __fmul_rn(R[2], scale);
    const float w  = fmaxf(__fmul_rn(R[3], scale), 1.0f);
    const float h  = fmaxf(__fmul_rn(R[4], scale), 1.0f);
    const float bin_h = __fdiv_rn(h, (float)OUT_H);
    const float bin_w = __fdiv_rn(w, (float)OUT_W);
    const float gy = (float)oh + (sy ? 0.75f : 0.25f);
    const float gx = (float)ow + (sx ? 0.75f : 0.25f);
    const float yy = __fadd_rn(__fmul_rn(-h, 0.5f), __fmul_rn(gy, bin_h));
    const float xx = __fadd_rn(__fmul_rn(-w, 0.5f), __fmul_rn(gx, bin_w));
    const float x = __fadd_rn(__fsub_rn(__fmul_rn(xx, ct), __fmul_rn(yy, st)), cx);
    const float y = __fadd_rn(__fadd_rn(__fmul_rn(xx, st), __fmul_rn(yy, ct)), cy);

    const bool valid = (y >= -1.0f) && (y <= (float)Hl) &&
                       (x >= -1.0f) && (x <= (float)Hl);
    float yc = fminf(fmaxf(y, 0.0f), (float)(Hl - 1));
    float xc = fminf(fmaxf(x, 0.0f), (float)(Hl - 1));
    int y0 = (int)floorf(yc);
    int x0 = (int)floorf(xc);
    float ly = yc - (float)y0;
    float lx = xc - (float)x0;
    if (y0 >= Hl - 1) { y0 = Hl - 2; ly = 1.0f; }
    if (x0 >= Hl - 1) { x0 = Hl - 2; lx = 1.0f; }
    const float hy = 1.0f - ly, hx = 1.0f - lx;
    const float sc = valid ? 0.25f : 0.0f;  // fold 1/ns^2 sample mean

    s_desc[j] = make_uint4(
        (unsigned)((pixoff + (b * Hl + y0) * Hl + x0) * (NCH * 2)),  // byte off
        pk_rtn(sc * hy * hx, sc * hy * lx),
        pk_rtn(sc * ly * hx, sc * ly * lx), 0u);
  }
  __syncthreads();

  const int  wv   = threadIdx.x >> 6;
  const int  lane = threadIdx.x & 63;
  const char* ftb = (const char*)ft + ch2 * 256 + lane * 4;  // 2 channels / lane

  for (int ow = wv; ow < OUT_W; ow += 4) {
    const int dbase = ow * 16;
    unsigned tvA[16], tvB[16];

    // ---- prologue: issue L0 then L1 loads (32 VMEM in flight) ----
    const uint4 a0 = s_desc[dbase +  0], a1 = s_desc[dbase +  1],
                a2 = s_desc[dbase +  2], a3 = s_desc[dbase +  3];
    ISSUE16(tvA, a0, a1, a2, a3, 131072);
    const uint4 b0 = s_desc[dbase +  4], b1 = s_desc[dbase +  5],
                b2 = s_desc[dbase +  6], b3 = s_desc[dbase +  7];
    ISSUE16(tvB, b0, b1, b2, b3, 65536);

    // ---- L0 FMAs (tvA frees) ----
    h2_t m = {(_Float16)0, (_Float16)0};
    FMA16(m, tvA, a0, a1, a2, a3);

    // ---- issue L2 into tvA, then L1 FMAs ----
    const uint4 c0 = s_desc[dbase +  8], c1 = s_desc[dbase +  9],
                c2 = s_desc[dbase + 10], c3 = s_desc[dbase + 11];
    ISSUE16(tvA, c0, c1, c2, c3, 32768);
    h2_t a = {(_Float16)0, (_Float16)0};
    FMA16(a, tvB, b0, b1, b2, b3);
    m = __builtin_elementwise_max(m, a);

    // ---- issue L3 into tvB, then L2 FMAs ----
    const uint4 d0 = s_desc[dbase + 12], d1 = s_desc[dbase + 13],
                d2 = s_desc[dbase + 14], d3 = s_desc[dbase + 15];
    ISSUE16(tvB, d0, d1, d2, d3, 16384);
    a = (h2_t){(_Float16)0, (_Float16)0};
    FMA16(a, tvA, c0, c1, c2, c3);
    m = __builtin_elementwise_max(m, a);

    // ---- L3 FMAs ----
    a = (h2_t){(_Float16)0, (_Float16)0};
    FMA16(a, tvB, d0, d1, d2, d3);
    m = __builtin_elementwise_max(m, a);

    s_out[ow * 66 + lane] = h2_bits(m);  // 2-way banks, free
  }
  __syncthreads();

  // ---- near-coalesced transposed write-out (f16 -> f32) ----
  const size_t outbase = (size_t)n * NCH * NBINS + (size_t)ch2 * 128 * NBINS +
                         (size_t)oh * OUT_W;
  const _Float16* sh = (const _Float16*)s_out;
#pragma unroll
  for (int j = 0; j < 18; ++j) {
    const int idx = threadIdx.x + j * 256;  // 0..4607, guard 4480
    if (idx < 128 * OUT_W) {
      const int cc = idx / OUT_W;           // magic-mul const div
      const int ww = idx - cc * OUT_W;
      out[outbase + (size_t)cc * NBINS + ww] = (float)sh[ww * 132 + cc];
    }
  }
}

// ---------------------------------------------------------------------------
extern "C" void kernel_launch(void* const* d_in, const int* in_sizes, int n_in,
                              void* d_out, int out_size, void* d_ws, size_t ws_size,
                              hipStream_t stream) {
  const float* f0 = (const float*)d_in[0];
  const float* f1 = (const float*)d_in[1];
  const float* f2 = (const float*)d_in[2];
  const float* f3 = (const float*)d_in[3];
  const float* rois = (const float*)d_in[4];
  ushort* ws = (ushort*)d_ws;
  float* out = (float*)d_out;

  transpose_all<<<10880, 256, 0, stream>>>(f0, f1, f2, f3, ws);
  roi_align_rotated_max<<<7168, 256, 0, stream>>>(ws, rois, out);
}